// Round 2
// baseline (381.139 us; speedup 1.0000x reference)
//
#include <hip/hip_runtime.h>
#include <cstdint>
#include <cstddef>

static constexpr int N1 = 40000;
static constexpr int N2 = 10000;
static constexpr int KNN = 16;
static constexpr float EPS = 1e-5f;

// Workspace layout (float offsets)
static constexpr size_t OFF_Y1  = 0;          // N1*64 raw linear1 output
static constexpr size_t OFF_Y2  = 2560000;    // N2*64 raw linear2 output
static constexpr size_t OFF_X2I = 3200000;    // N1*64
static constexpr size_t OFF_XQ  = 5760000;    // N1*64
static constexpr size_t OFF_XK  = 8320000;    // N1*64
static constexpr size_t OFF_XVP = 10880000;   // N1*64 (PERMUTED: [j][d*8+s])
static constexpr size_t OFF_W1B = 13440000;   // N1*KNN*8
static constexpr size_t OFF_ST  = 18560000;   // stats: st1(128) st2(128) st0(128) stw1(64 shadows)

// ---------------------------------------------------------------------------
// GEMM + fused column stats: Y = X@W + B, atomicAdd per-channel sum/sumsq
// ---------------------------------------------------------------------------
template<int CIN, int RPT>
__global__ __launch_bounds__(256) void gemm_stats_k(const float* __restrict__ X,
                                                    const float* __restrict__ W,
                                                    const float* __restrict__ B,
                                                    float* __restrict__ Y,
                                                    float* __restrict__ stats, int N)
{
    constexpr int ROWS = 16 * RPT;
    __shared__ float Ws[CIN * 64];
    __shared__ float Xs[ROWS][CIN + 1];
    __shared__ float red[16][64];

    for (int t = threadIdx.x; t < CIN * 64; t += 256) Ws[t] = W[t];
    const int base = blockIdx.x * ROWS;
    for (int f = threadIdx.x; f < ROWS * CIN / 4; f += 256) {
        int e = f * 4;
        int r = e / CIN, col = e % CIN;
        int grow = base + r;
        float4 v = make_float4(0.f, 0.f, 0.f, 0.f);
        if (grow < N) v = *(const float4*)(X + (size_t)grow * CIN + col);
        Xs[r][col + 0] = v.x; Xs[r][col + 1] = v.y;
        Xs[r][col + 2] = v.z; Xs[r][col + 3] = v.w;
    }
    __syncthreads();

    const int cg = threadIdx.x & 15, rg = threadIdx.x >> 4;
    float4 bv = *(const float4*)(B + cg * 4);
    float acc[RPT][4];
#pragma unroll
    for (int j = 0; j < RPT; j++) {
        acc[j][0] = bv.x; acc[j][1] = bv.y; acc[j][2] = bv.z; acc[j][3] = bv.w;
    }
#pragma unroll 8
    for (int k = 0; k < CIN; k++) {
        float4 w4 = *(const float4*)&Ws[k * 64 + cg * 4];
#pragma unroll
        for (int j = 0; j < RPT; j++) {
            float x = Xs[rg * RPT + j][k];
            acc[j][0] += x * w4.x; acc[j][1] += x * w4.y;
            acc[j][2] += x * w4.z; acc[j][3] += x * w4.w;
        }
    }

    float s[4] = {0.f, 0.f, 0.f, 0.f}, s2[4] = {0.f, 0.f, 0.f, 0.f};
#pragma unroll
    for (int j = 0; j < RPT; j++) {
        int r = base + rg * RPT + j;
        if (r < N) {
            *(float4*)(Y + (size_t)r * 64 + cg * 4) =
                make_float4(acc[j][0], acc[j][1], acc[j][2], acc[j][3]);
#pragma unroll
            for (int m = 0; m < 4; m++) { s[m] += acc[j][m]; s2[m] += acc[j][m] * acc[j][m]; }
        }
    }
    *(float4*)&red[rg][cg * 4] = make_float4(s[0], s[1], s[2], s[3]);
    __syncthreads();
    if (threadIdx.x < 64) {
        float t = 0.f;
#pragma unroll
        for (int g = 0; g < 16; g++) t += red[g][threadIdx.x];
        atomicAdd(&stats[threadIdx.x], t);
    }
    __syncthreads();
    *(float4*)&red[rg][cg * 4] = make_float4(s2[0], s2[1], s2[2], s2[3]);
    __syncthreads();
    if (threadIdx.x < 64) {
        float t = 0.f;
#pragma unroll
        for (int g = 0; g < 16; g++) t += red[g][threadIdx.x];
        atomicAdd(&stats[64 + threadIdx.x], t);
    }
}

// ---------------------------------------------------------------------------
// GEMM with BN+ReLU applied to X on load: Y = relu(bn(X)) @ W + B
// ---------------------------------------------------------------------------
__global__ __launch_bounds__(256) void gemm_bnx_k(const float* __restrict__ X,
                                                  const float* __restrict__ stats,
                                                  const float* __restrict__ g,
                                                  const float* __restrict__ be,
                                                  const float* __restrict__ W,
                                                  const float* __restrict__ B,
                                                  float* __restrict__ Y, int N, float invN)
{
    __shared__ float Ws[64 * 64];
    __shared__ float Xs[64][65];
    for (int t = threadIdx.x; t < 64 * 64; t += 256) Ws[t] = W[t];

    const int colf = (threadIdx.x * 4) & 63;
    float sc[4], sh[4];
#pragma unroll
    for (int m = 0; m < 4; m++) {
        int c = colf + m;
        float mean = stats[c] * invN;
        float var = stats[64 + c] * invN - mean * mean;
        float sg = g[c] * rsqrtf(var + EPS);
        sc[m] = sg; sh[m] = be[c] - mean * sg;
    }
    const int base = blockIdx.x * 64;
    for (int f = threadIdx.x; f < 64 * 64 / 4; f += 256) {
        int e = f * 4;
        int r = e >> 6, col = e & 63;
        float4 v = *(const float4*)(X + (size_t)(base + r) * 64 + col);
        Xs[r][col + 0] = fmaxf(v.x * sc[0] + sh[0], 0.f);
        Xs[r][col + 1] = fmaxf(v.y * sc[1] + sh[1], 0.f);
        Xs[r][col + 2] = fmaxf(v.z * sc[2] + sh[2], 0.f);
        Xs[r][col + 3] = fmaxf(v.w * sc[3] + sh[3], 0.f);
    }
    __syncthreads();

    const int cg = threadIdx.x & 15, rg = threadIdx.x >> 4;
    float4 bv = *(const float4*)(B + cg * 4);
    float acc[4][4];
#pragma unroll
    for (int j = 0; j < 4; j++) {
        acc[j][0] = bv.x; acc[j][1] = bv.y; acc[j][2] = bv.z; acc[j][3] = bv.w;
    }
#pragma unroll 8
    for (int k = 0; k < 64; k++) {
        float4 w4 = *(const float4*)&Ws[k * 64 + cg * 4];
#pragma unroll
        for (int j = 0; j < 4; j++) {
            float x = Xs[rg * 4 + j][k];
            acc[j][0] += x * w4.x; acc[j][1] += x * w4.y;
            acc[j][2] += x * w4.z; acc[j][3] += x * w4.w;
        }
    }
#pragma unroll
    for (int j = 0; j < 4; j++) {
        int r = base + rg * 4 + j;
        *(float4*)(Y + (size_t)r * 64 + cg * 4) =
            make_float4(acc[j][0], acc[j][1], acc[j][2], acc[j][3]);
    }
}

// ---------------------------------------------------------------------------
// Fused k/v GEMM: Yk = X@Wk + bk (normal layout), Yvp = X@Wv + bv (permuted)
// ---------------------------------------------------------------------------
__global__ __launch_bounds__(256) void gemm_kv_k(const float* __restrict__ X,
                                                 const float* __restrict__ Wk_,
                                                 const float* __restrict__ bk_,
                                                 const float* __restrict__ Wv_,
                                                 const float* __restrict__ bv_,
                                                 float* __restrict__ Yk,
                                                 float* __restrict__ Yvp, int N)
{
    __shared__ float Wks[64 * 64];
    __shared__ float Wvs[64 * 64];
    __shared__ float Xs[64][65];
    for (int t = threadIdx.x; t < 64 * 64; t += 256) { Wks[t] = Wk_[t]; Wvs[t] = Wv_[t]; }
    const int base = blockIdx.x * 64;
    for (int f = threadIdx.x; f < 64 * 64 / 4; f += 256) {
        int e = f * 4;
        int r = e >> 6, col = e & 63;
        float4 v = *(const float4*)(X + (size_t)(base + r) * 64 + col);
        Xs[r][col + 0] = v.x; Xs[r][col + 1] = v.y;
        Xs[r][col + 2] = v.z; Xs[r][col + 3] = v.w;
    }
    __syncthreads();

    const int cg = threadIdx.x & 15, rg = threadIdx.x >> 4;
    float4 bk4 = *(const float4*)(bk_ + cg * 4);
    float4 bv4 = *(const float4*)(bv_ + cg * 4);
    float ak[4][4], av[4][4];
#pragma unroll
    for (int j = 0; j < 4; j++) {
        ak[j][0] = bk4.x; ak[j][1] = bk4.y; ak[j][2] = bk4.z; ak[j][3] = bk4.w;
        av[j][0] = bv4.x; av[j][1] = bv4.y; av[j][2] = bv4.z; av[j][3] = bv4.w;
    }
#pragma unroll 4
    for (int k = 0; k < 64; k++) {
        float4 wk4 = *(const float4*)&Wks[k * 64 + cg * 4];
        float4 wv4 = *(const float4*)&Wvs[k * 64 + cg * 4];
#pragma unroll
        for (int j = 0; j < 4; j++) {
            float x = Xs[rg * 4 + j][k];
            ak[j][0] += x * wk4.x; ak[j][1] += x * wk4.y;
            ak[j][2] += x * wk4.z; ak[j][3] += x * wk4.w;
            av[j][0] += x * wv4.x; av[j][1] += x * wv4.y;
            av[j][2] += x * wv4.z; av[j][3] += x * wv4.w;
        }
    }
#pragma unroll
    for (int j = 0; j < 4; j++) {
        int r = base + rg * 4 + j;
        *(float4*)(Yk + (size_t)r * 64 + cg * 4) =
            make_float4(ak[j][0], ak[j][1], ak[j][2], ak[j][3]);
#pragma unroll
        for (int m = 0; m < 4; m++) {
            int c = cg * 4 + m;
            int pc = (c & 7) * 8 + (c >> 3); // channel c=s*8+d -> [d*8+s]
            Yvp[(size_t)r * 64 + pc] = av[j][m];
        }
    }
}

// ---------------------------------------------------------------------------
// 3-NN interpolation with BN+ReLU applied to gathered y2 rows
// ---------------------------------------------------------------------------
__global__ __launch_bounds__(256) void interp_bn_k(const float* __restrict__ p1,
                                                   const float* __restrict__ p2,
                                                   const int* __restrict__ iidx,
                                                   const float* __restrict__ y2,
                                                   const float* __restrict__ st2,
                                                   const float* __restrict__ g2,
                                                   const float* __restrict__ be2,
                                                   float* __restrict__ x2i)
{
    const int i = blockIdx.x * 4 + (threadIdx.x >> 6);
    const int c = threadIdx.x & 63;
    float mean = st2[c] * (1.f / N2);
    float var = st2[64 + c] * (1.f / N2) - mean * mean;
    float sg = g2[c] * rsqrtf(var + EPS);
    float sh = be2[c] - mean * sg;

    int j0 = iidx[i * 3 + 0], j1 = iidx[i * 3 + 1], j2 = iidx[i * 3 + 2];
    float ax = p1[i * 3 + 0], ay = p1[i * 3 + 1], az = p1[i * 3 + 2];
    float dx, dy, dz;
    dx = ax - p2[j0 * 3 + 0]; dy = ay - p2[j0 * 3 + 1]; dz = az - p2[j0 * 3 + 2];
    float w0 = 1.f / (sqrtf(dx * dx + dy * dy + dz * dz) + 1e-8f);
    dx = ax - p2[j1 * 3 + 0]; dy = ay - p2[j1 * 3 + 1]; dz = az - p2[j1 * 3 + 2];
    float w1 = 1.f / (sqrtf(dx * dx + dy * dy + dz * dz) + 1e-8f);
    dx = ax - p2[j2 * 3 + 0]; dy = ay - p2[j2 * 3 + 1]; dz = az - p2[j2 * 3 + 2];
    float w2 = 1.f / (sqrtf(dx * dx + dy * dy + dz * dz) + 1e-8f);
    float inv = 1.f / (w0 + w1 + w2);
    float h0 = fmaxf(y2[(size_t)j0 * 64 + c] * sg + sh, 0.f);
    float h1 = fmaxf(y2[(size_t)j1 * 64 + c] * sg + sh, 0.f);
    float h2 = fmaxf(y2[(size_t)j2 * 64 + c] * sg + sh, 0.f);
    x2i[(size_t)i * 64 + c] = inv * (w0 * h0 + w1 * h1 + w2 * h2);
}

// ---------------------------------------------------------------------------
// Stats of w = xk[knn[i,k]] - xq[i]: wave-per-node, lane=(k*4+q), 4 nodes/wave
// grid = 2500 blocks exactly (2500*4 waves*4 nodes = 40000)
// ---------------------------------------------------------------------------
__global__ __launch_bounds__(256) void wstats_k(const float* __restrict__ xq,
                                                const float* __restrict__ xk,
                                                const int* __restrict__ knn,
                                                float* __restrict__ st0)
{
    const int lane = threadIdx.x & 63, wv = threadIdx.x >> 6;
    const int k = lane >> 2, q = lane & 3;
    float s[16], s2[16];
#pragma unroll
    for (int m = 0; m < 16; m++) { s[m] = 0.f; s2[m] = 0.f; }

    const int ibase = blockIdx.x * 16 + wv * 4;
    for (int n = 0; n < 4; n++) {
        int i = ibase + n;
        int j = knn[i * KNN + k];
        const float* qp = xq + (size_t)i * 64 + q * 16;
        const float* kp = xk + (size_t)j * 64 + q * 16;
        float qr[16], kr[16];
        *(float4*)&qr[0]  = *(const float4*)(qp);
        *(float4*)&qr[4]  = *(const float4*)(qp + 4);
        *(float4*)&qr[8]  = *(const float4*)(qp + 8);
        *(float4*)&qr[12] = *(const float4*)(qp + 12);
        *(float4*)&kr[0]  = *(const float4*)(kp);
        *(float4*)&kr[4]  = *(const float4*)(kp + 4);
        *(float4*)&kr[8]  = *(const float4*)(kp + 8);
        *(float4*)&kr[12] = *(const float4*)(kp + 12);
#pragma unroll
        for (int m = 0; m < 16; m++) {
            float w = kr[m] - qr[m];
            s[m] += w; s2[m] += w * w;
        }
    }
#pragma unroll
    for (int off = 4; off <= 32; off <<= 1) {
#pragma unroll
        for (int m = 0; m < 16; m++) {
            s[m] += __shfl_xor(s[m], off);
            s2[m] += __shfl_xor(s2[m], off);
        }
    }
    __shared__ float red[4][4][32];
    if (k == 0) {
#pragma unroll
        for (int m = 0; m < 16; m++) { red[wv][q][m] = s[m]; red[wv][q][16 + m] = s2[m]; }
    }
    __syncthreads();
    if (threadIdx.x < 128) {
        int c = threadIdx.x & 63, issq = threadIdx.x >> 6;
        int qq = c >> 4, m = c & 15;
        float t = red[0][qq][issq * 16 + m] + red[1][qq][issq * 16 + m] +
                  red[2][qq][issq * 16 + m] + red[3][qq][issq * 16 + m];
        atomicAdd(&st0[threadIdx.x], t);
    }
}

// ---------------------------------------------------------------------------
// w1 = relu(bn0(xk_g - xq)) @ Ww1 + bw1 -> w1b; + stats of w1 (sharded x4)
// wave-per-node, lane=(k*4+q); lane owns channels q*16..q*16+15
// ---------------------------------------------------------------------------
__global__ __launch_bounds__(256) void wmlp1_k(const float* __restrict__ xq,
                                               const float* __restrict__ xk,
                                               const int* __restrict__ knn,
                                               const float* __restrict__ st0,
                                               const float* __restrict__ gw0,
                                               const float* __restrict__ bw0,
                                               const float* __restrict__ Ww1,
                                               const float* __restrict__ bw1,
                                               float* __restrict__ w1b,
                                               float* __restrict__ stw1)
{
    const int lane = threadIdx.x & 63, wv = threadIdx.x >> 6;
    const int k = lane >> 2, q = lane & 3;
    const float cinv = 1.f / (float)(N1 * KNN);

    float sc0[16], sh0[16];
#pragma unroll
    for (int m = 0; m < 16; m++) {
        int ch = q * 16 + m;
        float mean = st0[ch] * cinv;
        float var = st0[64 + ch] * cinv - mean * mean;
        float sg = gw0[ch] * rsqrtf(var + EPS);
        sc0[m] = sg; sh0[m] = bw0[ch] - mean * sg;
    }
    float bias[8];
#pragma unroll
    for (int d = 0; d < 8; d++) bias[d] = bw1[d];
    float sacc[8], s2acc[8];
#pragma unroll
    for (int d = 0; d < 8; d++) { sacc[d] = 0.f; s2acc[d] = 0.f; }

    const int ibase = blockIdx.x * 16 + wv * 4;
    for (int n = 0; n < 4; n++) {
        int i = ibase + n;
        int j = knn[i * KNN + k];
        const float* qp = xq + (size_t)i * 64 + q * 16;
        const float* kp = xk + (size_t)j * 64 + q * 16;
        float qr[16], kr[16];
        *(float4*)&qr[0]  = *(const float4*)(qp);
        *(float4*)&qr[4]  = *(const float4*)(qp + 4);
        *(float4*)&qr[8]  = *(const float4*)(qp + 8);
        *(float4*)&qr[12] = *(const float4*)(qp + 12);
        *(float4*)&kr[0]  = *(const float4*)(kp);
        *(float4*)&kr[4]  = *(const float4*)(kp + 4);
        *(float4*)&kr[8]  = *(const float4*)(kp + 8);
        *(float4*)&kr[12] = *(const float4*)(kp + 12);

        float p[8];
#pragma unroll
        for (int d = 0; d < 8; d++) p[d] = 0.f;
#pragma unroll
        for (int m = 0; m < 16; m++) {
            float u = (kr[m] - qr[m]) * sc0[m] + sh0[m];
            u = fmaxf(u, 0.f);
            const float* wr = Ww1 + (q * 16 + m) * 8;
            float4 wa = *(const float4*)wr;
            float4 wb = *(const float4*)(wr + 4);
            p[0] += u * wa.x; p[1] += u * wa.y; p[2] += u * wa.z; p[3] += u * wa.w;
            p[4] += u * wb.x; p[5] += u * wb.y; p[6] += u * wb.z; p[7] += u * wb.w;
        }
#pragma unroll
        for (int d = 0; d < 8; d++) p[d] += __shfl_xor(p[d], 1);
#pragma unroll
        for (int d = 0; d < 8; d++) p[d] += __shfl_xor(p[d], 2);
#pragma unroll
        for (int d = 0; d < 8; d++) {
            p[d] += bias[d];
            sacc[d] += p[d];
            s2acc[d] += p[d] * p[d];
        }
        float* wp = w1b + ((size_t)i * KNN + k) * 8;
        if (q == 0) *(float4*)wp = make_float4(p[0], p[1], p[2], p[3]);
        if (q == 1) *(float4*)(wp + 4) = make_float4(p[4], p[5], p[6], p[7]);
    }
    // sum over k lanes (each lane accumulated only its own k; q-copies identical)
#pragma unroll
    for (int off = 4; off <= 32; off <<= 1) {
#pragma unroll
        for (int d = 0; d < 8; d++) {
            sacc[d] += __shfl_xor(sacc[d], off);
            s2acc[d] += __shfl_xor(s2acc[d], off);
        }
    }
    __shared__ float red[4][16];
    if (lane == 0) {
#pragma unroll
        for (int d = 0; d < 8; d++) { red[wv][d] = sacc[d]; red[wv][8 + d] = s2acc[d]; }
    }
    __syncthreads();
    if (threadIdx.x < 16) {
        float t = red[0][threadIdx.x] + red[1][threadIdx.x] +
                  red[2][threadIdx.x] + red[3][threadIdx.x];
        atomicAdd(&stw1[(blockIdx.x & 3) * 16 + threadIdx.x], t);
    }
}

// ---------------------------------------------------------------------------
// Final: bn1+relu -> @Ww2 -> softmax over k -> weighted xvp agg -> + residual
// wave-per-node; lane=(k*4+q) owns output planes d = q*2, q*2+1
// residual x1h recomputed from raw y1 + st1
// ---------------------------------------------------------------------------
__global__ __launch_bounds__(256) void attn_k(const float* __restrict__ w1b,
                                              const float* __restrict__ stw1,
                                              const float* __restrict__ gw1,
                                              const float* __restrict__ bew1,
                                              const float* __restrict__ Ww2,
                                              const float* __restrict__ bw2,
                                              const int* __restrict__ knn,
                                              const float* __restrict__ xvp,
                                              const float* __restrict__ y1,
                                              const float* __restrict__ st1,
                                              const float* __restrict__ g1,
                                              const float* __restrict__ be1,
                                              float* __restrict__ out)
{
    const int lane = threadIdx.x & 63, wv = threadIdx.x >> 6;
    const int k = lane >> 2, q = lane & 3;
    const float cinv = 1.f / (float)(N1 * KNN);

    float sc1[8], sh1[8];
#pragma unroll
    for (int e = 0; e < 8; e++) {
        float ssum  = stw1[e] + stw1[16 + e] + stw1[32 + e] + stw1[48 + e];
        float s2sum = stw1[8 + e] + stw1[24 + e] + stw1[40 + e] + stw1[56 + e];
        float mean = ssum * cinv;
        float var = s2sum * cinv - mean * mean;
        float sg = gw1[e] * rsqrtf(var + EPS);
        sc1[e] = sg; sh1[e] = bew1[e] - mean * sg;
    }
    float w2c0[8], w2c1[8];
#pragma unroll
    for (int e = 0; e < 8; e++) { w2c0[e] = Ww2[e * 8 + q * 2]; w2c1[e] = Ww2[e * 8 + q * 2 + 1]; }
    const float b20 = bw2[q * 2], b21 = bw2[q * 2 + 1];

    // residual BN constants for channel = lane
    float meanr = st1[lane] * (1.f / N1);
    float varr = st1[64 + lane] * (1.f / N1) - meanr * meanr;
    float sgr = g1[lane] * rsqrtf(varr + EPS);
    float shr = be1[lane] - meanr * sgr;

    __shared__ float lds[4][64];
    const int ibase = blockIdx.x * 16 + wv * 4;
    for (int n = 0; n < 4; n++) {
        int i = ibase + n;
        int j = knn[i * KNN + k];
        const float* wp = w1b + ((size_t)i * KNN + k) * 8;
        float w1v[8];
        *(float4*)&w1v[0] = *(const float4*)wp;
        *(float4*)&w1v[4] = *(const float4*)(wp + 4);
        float a0 = b20, a1 = b21;
#pragma unroll
        for (int e = 0; e < 8; e++) {
            float v = fmaxf(w1v[e] * sc1[e] + sh1[e], 0.f);
            a0 += v * w2c0[e]; a1 += v * w2c1[e];
        }
        // softmax over k (lanes stride 4, same q)
        float mx0 = a0, mx1 = a1;
#pragma unroll
        for (int off = 4; off <= 32; off <<= 1) {
            mx0 = fmaxf(mx0, __shfl_xor(mx0, off));
            mx1 = fmaxf(mx1, __shfl_xor(mx1, off));
        }
        float e0 = __expf(a0 - mx0), e1 = __expf(a1 - mx1);
        float s0 = e0, s1 = e1;
#pragma unroll
        for (int off = 4; off <= 32; off <<= 1) {
            s0 += __shfl_xor(s0, off);
            s1 += __shfl_xor(s1, off);
        }
        float wg0 = e0 / s0, wg1 = e1 / s1;

        const float* vp = xvp + (size_t)j * 64 + q * 16;
        float4 v0 = *(const float4*)vp;
        float4 v1 = *(const float4*)(vp + 4);
        float4 v2 = *(const float4*)(vp + 8);
        float4 v3 = *(const float4*)(vp + 12);
        float acc[16];
        acc[0] = wg0 * v0.x; acc[1] = wg0 * v0.y; acc[2] = wg0 * v0.z; acc[3] = wg0 * v0.w;
        acc[4] = wg0 * v1.x; acc[5] = wg0 * v1.y; acc[6] = wg0 * v1.z; acc[7] = wg0 * v1.w;
        acc[8] = wg1 * v2.x; acc[9] = wg1 * v2.y; acc[10] = wg1 * v2.z; acc[11] = wg1 * v2.w;
        acc[12] = wg1 * v3.x; acc[13] = wg1 * v3.y; acc[14] = wg1 * v3.z; acc[15] = wg1 * v3.w;
#pragma unroll
        for (int off = 4; off <= 32; off <<= 1) {
#pragma unroll
            for (int t = 0; t < 16; t++) acc[t] += __shfl_xor(acc[t], off);
        }
        if (k == 0) {
#pragma unroll
            for (int s = 0; s < 8; s++) {
                lds[wv][s * 8 + q * 2] = acc[s];       // d = q*2
                lds[wv][s * 8 + q * 2 + 1] = acc[8 + s]; // d = q*2+1
            }
        }
        __syncthreads();
        float yv = y1[(size_t)i * 64 + lane];
        float xh = fmaxf(yv * sgr + shr, 0.f);
        out[(size_t)i * 64 + lane] = xh + lds[wv][lane];
        __syncthreads();
    }
}

// ---------------------------------------------------------------------------
extern "C" void kernel_launch(void* const* d_in, const int* in_sizes, int n_in,
                              void* d_out, int out_size, void* d_ws, size_t ws_size,
                              hipStream_t stream)
{
    const float* p1   = (const float*)d_in[0];
    const float* x1   = (const float*)d_in[1];
    const float* p2   = (const float*)d_in[2];
    const float* x2   = (const float*)d_in[3];
    const int*   knn  = (const int*)d_in[4];
    const int*   iidx = (const int*)d_in[5];
    const float* W1   = (const float*)d_in[6];
    const float* b1   = (const float*)d_in[7];
    const float* g1   = (const float*)d_in[8];
    const float* be1  = (const float*)d_in[9];
    const float* W2   = (const float*)d_in[10];
    const float* b2   = (const float*)d_in[11];
    const float* g2   = (const float*)d_in[12];
    const float* be2  = (const float*)d_in[13];
    const float* Wq   = (const float*)d_in[14];
    const float* bq   = (const float*)d_in[15];
    const float* Wk   = (const float*)d_in[16];
    const float* bk   = (const float*)d_in[17];
    const float* Wv   = (const float*)d_in[18];
    const float* bv   = (const float*)d_in[19];
    const float* gw0  = (const float*)d_in[20];
    const float* bw0  = (const float*)d_in[21];
    const float* Ww1  = (const float*)d_in[22];
    const float* bw1  = (const float*)d_in[23];
    const float* gw1  = (const float*)d_in[24];
    const float* bew1 = (const float*)d_in[25];
    const float* Ww2  = (const float*)d_in[26];
    const float* bw2  = (const float*)d_in[27];

    float* ws   = (float*)d_ws;
    float* y1   = ws + OFF_Y1;
    float* y2   = ws + OFF_Y2;
    float* x2i  = ws + OFF_X2I;
    float* xq   = ws + OFF_XQ;
    float* xk   = ws + OFF_XK;
    float* xvp  = ws + OFF_XVP;
    float* w1b  = ws + OFF_W1B;
    float* st1  = ws + OFF_ST;
    float* st2  = st1 + 128;
    float* st0  = st1 + 256;
    float* stw1 = st1 + 384; // 64 floats (4 shadows of 16)
    float* outp = (float*)d_out;

    hipMemsetAsync(st1, 0, 512 * sizeof(float), stream);

    gemm_stats_k<64, 4><<<N1 / 64, 256, 0, stream>>>(x1, W1, b1, y1, st1, N1);
    gemm_stats_k<128, 2><<<(N2 + 31) / 32, 256, 0, stream>>>(x2, W2, b2, y2, st2, N2);
    interp_bn_k<<<N1 / 4, 256, 0, stream>>>(p1, p2, iidx, y2, st2, g2, be2, x2i);
    gemm_bnx_k<<<N1 / 64, 256, 0, stream>>>(y1, st1, g1, be1, Wq, bq, xq, N1, 1.f / N1);
    gemm_kv_k<<<N1 / 64, 256, 0, stream>>>(x2i, Wk, bk, Wv, bv, xk, xvp, N1);
    wstats_k<<<N1 / 16, 256, 0, stream>>>(xq, xk, knn, st0);
    wmlp1_k<<<N1 / 16, 256, 0, stream>>>(xq, xk, knn, st0, gw0, bw0, Ww1, bw1, w1b, stw1);
    attn_k<<<N1 / 16, 256, 0, stream>>>(w1b, stw1, gw1, bew1, Ww2, bw2, knn, xvp, y1, st1, g1, be1, outp);
}

// Round 4
// 316.950 us; speedup vs baseline: 1.2025x; 1.2025x over previous
//
#include <hip/hip_runtime.h>
#include <cstdint>
#include <cstddef>

static constexpr int N1 = 40000;
static constexpr int N2 = 10000;
static constexpr int KNN = 16;
static constexpr float EPS = 1e-5f;

// Workspace layout (float offsets)
static constexpr size_t OFF_Y1  = 0;          // N1*64 raw linear1 output
static constexpr size_t OFF_Y2  = 2560000;    // N2*64 raw linear2 output
static constexpr size_t OFF_XQ  = 5760000;    // N1*64
static constexpr size_t OFF_XK  = 8320000;    // N1*64
static constexpr size_t OFF_XVP = 10880000;   // N1*64 (PERMUTED: [j][d*8+s])
static constexpr size_t OFF_W1B = 13440000;   // N1*KNN*8
static constexpr size_t OFF_ST  = 18560000;   // st1(128) st2(128) st0(128) stw1(16)

// ---------------------------------------------------------------------------
// Stage 16 gathered rows (256B each) of `tab` into wave-private LDS buffer,
// bank-swizzled: row kk's logical 32B segment s lands at phys seg (s+kk)&7.
// ---------------------------------------------------------------------------
__device__ __forceinline__ void stage_rows(const float* __restrict__ tab,
                                           const int* __restrict__ knn,
                                           int node, float* __restrict__ buf,
                                           int lane)
{
    const int t4 = lane >> 4;
    const int c16 = lane & 15;
    const int seg = c16 >> 1, half = c16 & 1;
#pragma unroll
    for (int t = 0; t < 4; t++) {
        int kk = t * 4 + t4;
        int j = knn[node * KNN + kk];
        float4 v = *((const float4*)(tab + (size_t)j * 64) + c16);
        int ps = (seg + kk) & 7;
        *(float4*)(buf + kk * 64 + ps * 8 + half * 4) = v;
    }
}

// read logical 32B segment l8 of staged row k (two float4s)
__device__ __forceinline__ void read_seg(const float* __restrict__ buf, int k,
                                         int l8, float* __restrict__ u)
{
    const float* p = buf + k * 64 + (((l8 + k) & 7) << 3);
    *(float4*)&u[0] = *(const float4*)p;
    *(float4*)&u[4] = *(const float4*)(p + 4);
}

// ---------------------------------------------------------------------------
// Fused GEMM + column stats for linear1 (CIN=64) and linear2 (CIN=128).
// Biases dropped (BN cancels them). blocks [0,625) -> l1, [625,938) -> l2.
// ---------------------------------------------------------------------------
template<int CIN, int RPT>
__device__ __forceinline__ void gemm_stats_body(const float* __restrict__ X,
                                                const float* __restrict__ W,
                                                float* __restrict__ Y,
                                                float* __restrict__ stats,
                                                int N, int bidx, float* sm)
{
    constexpr int ROWS = 16 * RPT;
    constexpr int XST = CIN + 4;
    float* Ws = sm;
    float* Xs = sm + CIN * 64;

    for (int t = threadIdx.x; t < CIN * 64; t += 256) Ws[t] = W[t];
    const int base = bidx * ROWS;
    for (int f = threadIdx.x; f < ROWS * CIN / 4; f += 256) {
        int e = f * 4;
        int r = e / CIN, col = e % CIN;
        int grow = base + r;
        float4 v = make_float4(0.f, 0.f, 0.f, 0.f);
        if (grow < N) v = *(const float4*)(X + (size_t)grow * CIN + col);
        *(float4*)(Xs + r * XST + col) = v;
    }
    __syncthreads();

    const int cg = threadIdx.x & 15, rg = threadIdx.x >> 4;
    float acc[RPT][4];
#pragma unroll
    for (int j = 0; j < RPT; j++)
        acc[j][0] = acc[j][1] = acc[j][2] = acc[j][3] = 0.f;
#pragma unroll 8
    for (int k = 0; k < CIN; k++) {
        float4 w4 = *(const float4*)&Ws[k * 64 + cg * 4];
#pragma unroll
        for (int j = 0; j < RPT; j++) {
            float x = Xs[(rg * RPT + j) * XST + k];
            acc[j][0] += x * w4.x; acc[j][1] += x * w4.y;
            acc[j][2] += x * w4.z; acc[j][3] += x * w4.w;
        }
    }

    float s[4] = {0.f, 0.f, 0.f, 0.f}, s2[4] = {0.f, 0.f, 0.f, 0.f};
#pragma unroll
    for (int j = 0; j < RPT; j++) {
        int r = base + rg * RPT + j;
        if (r < N) {
            *(float4*)(Y + (size_t)r * 64 + cg * 4) =
                make_float4(acc[j][0], acc[j][1], acc[j][2], acc[j][3]);
#pragma unroll
            for (int m = 0; m < 4; m++) { s[m] += acc[j][m]; s2[m] += acc[j][m] * acc[j][m]; }
        }
    }
    __syncthreads();                       // done reading Ws -> reuse as red
    float* red = Ws;                       // [16][64]
    *(float4*)&red[rg * 64 + cg * 4] = make_float4(s[0], s[1], s[2], s[3]);
    __syncthreads();
    if (threadIdx.x < 64) {
        float t = 0.f;
#pragma unroll
        for (int g = 0; g < 16; g++) t += red[g * 64 + threadIdx.x];
        atomicAdd(&stats[threadIdx.x], t);
    }
    __syncthreads();
    *(float4*)&red[rg * 64 + cg * 4] = make_float4(s2[0], s2[1], s2[2], s2[3]);
    __syncthreads();
    if (threadIdx.x < 64) {
        float t = 0.f;
#pragma unroll
        for (int g = 0; g < 16; g++) t += red[g * 64 + threadIdx.x];
        atomicAdd(&stats[64 + threadIdx.x], t);
    }
}

__global__ __launch_bounds__(256) void stats12_k(const float* __restrict__ x1,
                                                 const float* __restrict__ W1,
                                                 const float* __restrict__ x2,
                                                 const float* __restrict__ W2,
                                                 float* __restrict__ y1,
                                                 float* __restrict__ y2,
                                                 float* __restrict__ st1,
                                                 float* __restrict__ st2)
{
    __shared__ float sm[128 * 64 + 32 * 132];
    if (blockIdx.x < 625)
        gemm_stats_body<64, 4>(x1, W1, y1, st1, N1, blockIdx.x, sm);
    else
        gemm_stats_body<128, 2>(x2, W2, y2, st2, N2, blockIdx.x - 625, sm);
}

// ---------------------------------------------------------------------------
// Fused q-projection and (interp + k/v projection).
// blocks [0,625): xq = relu(bn1(y1)) @ Wq + bq
// blocks [625,1250): x2i = interp(relu(bn2(y2))); xk = x2i@Wk; xvp = perm(x2i@Wv + bv)
// LDS layout (12672 floats): [Wks 4096][Wvs 4096][Xs 64x68=4352][cst 128]
//   cst MUST be at 12544 (= 8192+4352); at 12288 it aliases Xs rows 60-63 (r3 bug).
// ---------------------------------------------------------------------------
__global__ __launch_bounds__(256) void qkv_k(const float* __restrict__ y1,
                                             const float* __restrict__ st1,
                                             const float* __restrict__ g1,
                                             const float* __restrict__ be1,
                                             const float* __restrict__ Wq,
                                             const float* __restrict__ bq,
                                             const float* __restrict__ p1,
                                             const float* __restrict__ p2,
                                             const int* __restrict__ iidx,
                                             const float* __restrict__ y2,
                                             const float* __restrict__ st2,
                                             const float* __restrict__ g2,
                                             const float* __restrict__ be2,
                                             const float* __restrict__ Wk_,
                                             const float* __restrict__ Wv_,
                                             const float* __restrict__ bv_,
                                             float* __restrict__ xq,
                                             float* __restrict__ xk,
                                             float* __restrict__ xvp)
{
    __shared__ float sm[12672];
    const int cg = threadIdx.x & 15, rg = threadIdx.x >> 4;

    if (blockIdx.x < 625) {
        float* Ws = sm;                 // 4096
        float* Xs = sm + 4096;          // 64 x 68 -> ends 8448
        float* cst = sm + 12544;        // sc[64], sh[64]
        for (int t = threadIdx.x; t < 4096; t += 256) Ws[t] = Wq[t];
        if (threadIdx.x < 64) {
            int c = threadIdx.x;
            float mean = st1[c] * (1.f / N1);
            float var = st1[64 + c] * (1.f / N1) - mean * mean;
            float sg = g1[c] * rsqrtf(var + EPS);
            cst[c] = sg; cst[64 + c] = be1[c] - mean * sg;
        }
        __syncthreads();
        const int base = blockIdx.x * 64;
        for (int f = threadIdx.x; f < 1024; f += 256) {
            int r = f >> 4, col = (f & 15) * 4;
            float4 v = *(const float4*)(y1 + (size_t)(base + r) * 64 + col);
            Xs[r * 68 + col + 0] = fmaxf(v.x * cst[col] + cst[64 + col], 0.f);
            Xs[r * 68 + col + 1] = fmaxf(v.y * cst[col + 1] + cst[64 + col + 1], 0.f);
            Xs[r * 68 + col + 2] = fmaxf(v.z * cst[col + 2] + cst[64 + col + 2], 0.f);
            Xs[r * 68 + col + 3] = fmaxf(v.w * cst[col + 3] + cst[64 + col + 3], 0.f);
        }
        __syncthreads();
        float4 bb = *(const float4*)(bq + cg * 4);
        float acc[4][4];
#pragma unroll
        for (int j = 0; j < 4; j++) {
            acc[j][0] = bb.x; acc[j][1] = bb.y; acc[j][2] = bb.z; acc[j][3] = bb.w;
        }
#pragma unroll 8
        for (int k = 0; k < 64; k++) {
            float4 w4 = *(const float4*)&Ws[k * 64 + cg * 4];
#pragma unroll
            for (int j = 0; j < 4; j++) {
                float x = Xs[(rg * 4 + j) * 68 + k];
                acc[j][0] += x * w4.x; acc[j][1] += x * w4.y;
                acc[j][2] += x * w4.z; acc[j][3] += x * w4.w;
            }
        }
#pragma unroll
        for (int j = 0; j < 4; j++) {
            int r = base + rg * 4 + j;
            *(float4*)(xq + (size_t)r * 64 + cg * 4) =
                make_float4(acc[j][0], acc[j][1], acc[j][2], acc[j][3]);
        }
    } else {
        float* Wks = sm;                // 4096
        float* Wvs = sm + 4096;         // 4096
        float* Xs = sm + 8192;          // 64 x 68 -> ends 12544
        float* cst = sm + 12544;        // sc2[64], sh2[64]
        for (int t = threadIdx.x; t < 4096; t += 256) { Wks[t] = Wk_[t]; Wvs[t] = Wv_[t]; }
        if (threadIdx.x < 64) {
            int c = threadIdx.x;
            float mean = st2[c] * (1.f / N2);
            float var = st2[64 + c] * (1.f / N2) - mean * mean;
            float sg = g2[c] * rsqrtf(var + EPS);
            cst[c] = sg; cst[64 + c] = be2[c] - mean * sg;
        }
        __syncthreads();
        const int base = (blockIdx.x - 625) * 64;
        {   // interp fill: thread = (row, quarter)
            int row = threadIdx.x >> 2, q4 = threadIdx.x & 3;
            int gi = base + row;
            int j0 = iidx[gi * 3 + 0], j1 = iidx[gi * 3 + 1], j2 = iidx[gi * 3 + 2];
            float ax = p1[gi * 3 + 0], ay = p1[gi * 3 + 1], az = p1[gi * 3 + 2];
            float dx, dy, dz;
            dx = ax - p2[j0 * 3 + 0]; dy = ay - p2[j0 * 3 + 1]; dz = az - p2[j0 * 3 + 2];
            float w0 = 1.f / (sqrtf(dx * dx + dy * dy + dz * dz) + 1e-8f);
            dx = ax - p2[j1 * 3 + 0]; dy = ay - p2[j1 * 3 + 1]; dz = az - p2[j1 * 3 + 2];
            float w1 = 1.f / (sqrtf(dx * dx + dy * dy + dz * dz) + 1e-8f);
            dx = ax - p2[j2 * 3 + 0]; dy = ay - p2[j2 * 3 + 1]; dz = az - p2[j2 * 3 + 2];
            float w2 = 1.f / (sqrtf(dx * dx + dy * dy + dz * dz) + 1e-8f);
            float inv = 1.f / (w0 + w1 + w2);
            w0 *= inv; w1 *= inv; w2 *= inv;
#pragma unroll
            for (int c4 = 0; c4 < 4; c4++) {
                int col = q4 * 16 + c4 * 4;
                float4 a = *(const float4*)(y2 + (size_t)j0 * 64 + col);
                float4 b = *(const float4*)(y2 + (size_t)j1 * 64 + col);
                float4 c = *(const float4*)(y2 + (size_t)j2 * 64 + col);
                float4 o;
                o.x = w0 * fmaxf(a.x * cst[col] + cst[64 + col], 0.f)
                    + w1 * fmaxf(b.x * cst[col] + cst[64 + col], 0.f)
                    + w2 * fmaxf(c.x * cst[col] + cst[64 + col], 0.f);
                o.y = w0 * fmaxf(a.y * cst[col + 1] + cst[64 + col + 1], 0.f)
                    + w1 * fmaxf(b.y * cst[col + 1] + cst[64 + col + 1], 0.f)
                    + w2 * fmaxf(c.y * cst[col + 1] + cst[64 + col + 1], 0.f);
                o.z = w0 * fmaxf(a.z * cst[col + 2] + cst[64 + col + 2], 0.f)
                    + w1 * fmaxf(b.z * cst[col + 2] + cst[64 + col + 2], 0.f)
                    + w2 * fmaxf(c.z * cst[col + 2] + cst[64 + col + 2], 0.f);
                o.w = w0 * fmaxf(a.w * cst[col + 3] + cst[64 + col + 3], 0.f)
                    + w1 * fmaxf(b.w * cst[col + 3] + cst[64 + col + 3], 0.f)
                    + w2 * fmaxf(c.w * cst[col + 3] + cst[64 + col + 3], 0.f);
                *(float4*)(Xs + row * 68 + col) = o;
            }
        }
        __syncthreads();
        float4 bv4 = *(const float4*)(bv_ + cg * 4);
        float ak[4][4], av[4][4];
#pragma unroll
        for (int j = 0; j < 4; j++) {
            ak[j][0] = ak[j][1] = ak[j][2] = ak[j][3] = 0.f;
            av[j][0] = bv4.x; av[j][1] = bv4.y; av[j][2] = bv4.z; av[j][3] = bv4.w;
        }
#pragma unroll 4
        for (int k = 0; k < 64; k++) {
            float4 wk4 = *(const float4*)&Wks[k * 64 + cg * 4];
            float4 wv4 = *(const float4*)&Wvs[k * 64 + cg * 4];
#pragma unroll
            for (int j = 0; j < 4; j++) {
                float x = Xs[(rg * 4 + j) * 68 + k];
                ak[j][0] += x * wk4.x; ak[j][1] += x * wk4.y;
                ak[j][2] += x * wk4.z; ak[j][3] += x * wk4.w;
                av[j][0] += x * wv4.x; av[j][1] += x * wv4.y;
                av[j][2] += x * wv4.z; av[j][3] += x * wv4.w;
            }
        }
#pragma unroll
        for (int j = 0; j < 4; j++) {
            int r = base + rg * 4 + j;
            *(float4*)(xk + (size_t)r * 64 + cg * 4) =
                make_float4(ak[j][0], ak[j][1], ak[j][2], ak[j][3]);
#pragma unroll
            for (int m = 0; m < 4; m++) {
                int c = cg * 4 + m;
                int pc = (c & 7) * 8 + (c >> 3);   // [s*8+d] -> [d*8+s]
                xvp[(size_t)r * 64 + pc] = av[j][m];
            }
        }
    }
}

// ---------------------------------------------------------------------------
// wstats: per-channel sum/sumsq of w = xk[knn]-xq via staged LDS gathers.
// block = 4 waves; wave = 8 nodes serial, double-buffered staging.
// lane = (kg = lane>>3) x (l8 = lane&7); l8 owns channels l8*8..+7.
// ---------------------------------------------------------------------------
__global__ __launch_bounds__(256, 4) void wstats_k(const float* __restrict__ xq,
                                                   const float* __restrict__ xk,
                                                   const int* __restrict__ knn,
                                                   float* __restrict__ st0)
{
    __shared__ float buf[4][2][1024];
    __shared__ float red[4][128];
    const int lane = threadIdx.x & 63, wv = threadIdx.x >> 6;
    const int kg = lane >> 3, l8 = lane & 7;
    const int nbase = blockIdx.x * 32 + wv * 8;

    float s[8], s2[8];
#pragma unroll
    for (int m = 0; m < 8; m++) { s[m] = 0.f; s2[m] = 0.f; }

    float qr[8], qrn[8];
    stage_rows(xk, knn, nbase, buf[wv][0], lane);
    *(float4*)&qr[0] = *(const float4*)(xq + (size_t)nbase * 64 + l8 * 8);
    *(float4*)&qr[4] = *(const float4*)(xq + (size_t)nbase * 64 + l8 * 8 + 4);

    for (int n = 0; n < 8; n++) {
        if (n < 7) {
            stage_rows(xk, knn, nbase + n + 1, buf[wv][(n + 1) & 1], lane);
            *(float4*)&qrn[0] = *(const float4*)(xq + (size_t)(nbase + n + 1) * 64 + l8 * 8);
            *(float4*)&qrn[4] = *(const float4*)(xq + (size_t)(nbase + n + 1) * 64 + l8 * 8 + 4);
        }
        const float* b = buf[wv][n & 1];
#pragma unroll
        for (int r = 0; r < 2; r++) {
            int k = kg + r * 8;
            float u[8];
            read_seg(b, k, l8, u);
#pragma unroll
            for (int m = 0; m < 8; m++) {
                float w = u[m] - qr[m];
                s[m] += w; s2[m] += w * w;
            }
        }
#pragma unroll
        for (int m = 0; m < 8; m++) qr[m] = qrn[m];
    }
#pragma unroll
    for (int off = 8; off <= 32; off <<= 1)
#pragma unroll
        for (int m = 0; m < 8; m++) {
            s[m] += __shfl_xor(s[m], off);
            s2[m] += __shfl_xor(s2[m], off);
        }
    if (kg == 0) {
#pragma unroll
        for (int m = 0; m < 8; m++) {
            red[wv][l8 * 8 + m] = s[m];
            red[wv][64 + l8 * 8 + m] = s2[m];
        }
    }
    __syncthreads();
    if (threadIdx.x < 128) {
        float t = red[0][threadIdx.x] + red[1][threadIdx.x] +
                  red[2][threadIdx.x] + red[3][threadIdx.x];
        atomicAdd(&st0[threadIdx.x], t);
    }
}

// ---------------------------------------------------------------------------
// wmlp1: w1[i,k,:] = relu(bn0(xk[knn]-xq)) @ Ww1   (bw1 dropped - BN cancels)
// Same staging as wstats; BN0 folded per node: u' = kr*sc0 + (sh0 - qr*sc0).
// ---------------------------------------------------------------------------
__global__ __launch_bounds__(256, 4) void wmlp1_k(const float* __restrict__ xq,
                                                  const float* __restrict__ xk,
                                                  const int* __restrict__ knn,
                                                  const float* __restrict__ st0,
                                                  const float* __restrict__ gw0,
                                                  const float* __restrict__ bw0,
                                                  const float* __restrict__ Ww1,
                                                  float* __restrict__ w1b)
{
    __shared__ float buf[4][2][1024];
    const int lane = threadIdx.x & 63, wv = threadIdx.x >> 6;
    const int kg = lane >> 3, l8 = lane & 7;
    const int nbase = blockIdx.x * 32 + wv * 8;
    const float cinv = 1.f / (float)(N1 * KNN);

    float sc0[8], sh0[8];
#pragma unroll
    for (int m = 0; m < 8; m++) {
        int ch = l8 * 8 + m;
        float mean = st0[ch] * cinv;
        float var = st0[64 + ch] * cinv - mean * mean;
        float sg = gw0[ch] * rsqrtf(var + EPS);
        sc0[m] = sg; sh0[m] = bw0[ch] - mean * sg;
    }
    float wW[8][8];
#pragma unroll
    for (int m = 0; m < 8; m++) {
        *(float4*)&wW[m][0] = *(const float4*)(Ww1 + (l8 * 8 + m) * 8);
        *(float4*)&wW[m][4] = *(const float4*)(Ww1 + (l8 * 8 + m) * 8 + 4);
    }

    float qsh[8], qshn[8];
    stage_rows(xk, knn, nbase, buf[wv][0], lane);
    {
        float q0[8];
        *(float4*)&q0[0] = *(const float4*)(xq + (size_t)nbase * 64 + l8 * 8);
        *(float4*)&q0[4] = *(const float4*)(xq + (size_t)nbase * 64 + l8 * 8 + 4);
#pragma unroll
        for (int m = 0; m < 8; m++) qsh[m] = sh0[m] - q0[m] * sc0[m];
    }

    for (int n = 0; n < 8; n++) {
        int i = nbase + n;
        if (n < 7) {
            stage_rows(xk, knn, i + 1, buf[wv][(n + 1) & 1], lane);
            float qn[8];
            *(float4*)&qn[0] = *(const float4*)(xq + (size_t)(i + 1) * 64 + l8 * 8);
            *(float4*)&qn[4] = *(const float4*)(xq + (size_t)(i + 1) * 64 + l8 * 8 + 4);
#pragma unroll
            for (int m = 0; m < 8; m++) qshn[m] = sh0[m] - qn[m] * sc0[m];
        }
        const float* b = buf[wv][n & 1];
#pragma unroll
        for (int r = 0; r < 2; r++) {
            int k = kg + r * 8;
            float u[8];
            read_seg(b, k, l8, u);
            float p[8];
#pragma unroll
            for (int d = 0; d < 8; d++) p[d] = 0.f;
#pragma unroll
            for (int m = 0; m < 8; m++) {
                float t = fmaxf(u[m] * sc0[m] + qsh[m], 0.f);
#pragma unroll
                for (int d = 0; d < 8; d++) p[d] += t * wW[m][d];
            }
#pragma unroll
            for (int d = 0; d < 8; d++) p[d] += __shfl_xor(p[d], 1);
#pragma unroll
            for (int d = 0; d < 8; d++) p[d] += __shfl_xor(p[d], 2);
#pragma unroll
            for (int d = 0; d < 8; d++) p[d] += __shfl_xor(p[d], 4);
            if (l8 == 0) {
                float* wp = w1b + ((size_t)i * KNN + k) * 8;
                *(float4*)wp = make_float4(p[0], p[1], p[2], p[3]);
                *(float4*)(wp + 4) = make_float4(p[4], p[5], p[6], p[7]);
            }
        }
#pragma unroll
        for (int m = 0; m < 8; m++) qsh[m] = qshn[m];
    }
}

// ---------------------------------------------------------------------------
// Streaming stats of w1b (sum/sumsq per d) -> stw1[16]
// ---------------------------------------------------------------------------
__global__ __launch_bounds__(256) void w1stats_k(const float* __restrict__ w1b,
                                                 float* __restrict__ stw1)
{
    float s[8], s2[8];
#pragma unroll
    for (int d = 0; d < 8; d++) { s[d] = 0.f; s2[d] = 0.f; }
    for (size_t r = blockIdx.x * 256 + threadIdx.x; r < (size_t)N1 * KNN;
         r += (size_t)gridDim.x * 256) {
        const float* p = w1b + r * 8;
        float4 a = *(const float4*)p;
        float4 b = *(const float4*)(p + 4);
        s[0] += a.x; s2[0] += a.x * a.x; s[1] += a.y; s2[1] += a.y * a.y;
        s[2] += a.z; s2[2] += a.z * a.z; s[3] += a.w; s2[3] += a.w * a.w;
        s[4] += b.x; s2[4] += b.x * b.x; s[5] += b.y; s2[5] += b.y * b.y;
        s[6] += b.z; s2[6] += b.z * b.z; s[7] += b.w; s2[7] += b.w * b.w;
    }
#pragma unroll
    for (int off = 1; off <= 32; off <<= 1)
#pragma unroll
        for (int d = 0; d < 8; d++) {
            s[d] += __shfl_xor(s[d], off);
            s2[d] += __shfl_xor(s2[d], off);
        }
    __shared__ float red[4][16];
    const int lane = threadIdx.x & 63, wv = threadIdx.x >> 6;
    if (lane == 0) {
#pragma unroll
        for (int d = 0; d < 8; d++) { red[wv][d] = s[d]; red[wv][8 + d] = s2[d]; }
    }
    __syncthreads();
    if (threadIdx.x < 16) {
        float t = red[0][threadIdx.x] + red[1][threadIdx.x] +
                  red[2][threadIdx.x] + red[3][threadIdx.x];
        atomicAdd(&stw1[threadIdx.x], t);
    }
}

// ---------------------------------------------------------------------------
// attn: bn1+relu -> @Ww2 (bw2 dropped; softmax-invariant) -> softmax over k
//       -> weighted xvp aggregation -> + relu(bn1(y1)) residual.
// lane (kg,l8): logits for k in {kg,kg+8}, d=l8; staged xvp + w1 rows.
// ---------------------------------------------------------------------------
__global__ __launch_bounds__(256, 4) void attn_k(const float* __restrict__ w1b,
                                                 const float* __restrict__ stw1,
                                                 const float* __restrict__ gw1,
                                                 const float* __restrict__ bew1,
                                                 const float* __restrict__ Ww2,
                                                 const int* __restrict__ knn,
                                                 const float* __restrict__ xvp,
                                                 const float* __restrict__ y1,
                                                 const float* __restrict__ st1,
                                                 const float* __restrict__ g1,
                                                 const float* __restrict__ be1,
                                                 float* __restrict__ out)
{
    __shared__ float vbuf[4][2][1024];
    __shared__ float wbuf[4][2][128];
    const int lane = threadIdx.x & 63, wv = threadIdx.x >> 6;
    const int kg = lane >> 3, l8 = lane & 7;
    const int nbase = blockIdx.x * 32 + wv * 8;
    const float cinv = 1.f / (float)(N1 * KNN);

    float sc1[8], sh1[8];
#pragma unroll
    for (int e = 0; e < 8; e++) {
        float mean = stw1[e] * cinv;
        float var = stw1[8 + e] * cinv - mean * mean;
        float sg = gw1[e] * rsqrtf(var + EPS);
        sc1[e] = sg; sh1[e] = bew1[e] - mean * sg;
    }
    float w2c[8];
#pragma unroll
    for (int e = 0; e < 8; e++) w2c[e] = Ww2[e * 8 + l8];

    float sgr[8], shr[8];
#pragma unroll
    for (int ss = 0; ss < 8; ss++) {
        int c = ss * 8 + l8;
        float mean = st1[c] * (1.f / N1);
        float var = st1[64 + c] * (1.f / N1) - mean * mean;
        float sg = g1[c] * rsqrtf(var + EPS);
        sgr[ss] = sg; shr[ss] = be1[c] - mean * sg;
    }

    float yr[8], yrn[8];
    stage_rows(xvp, knn, nbase, vbuf[wv][0], lane);
    if (lane < 32)
        *(float4*)&wbuf[wv][0][lane * 4] =
            *(const float4*)(w1b + (size_t)nbase * 128 + lane * 4);
#pragma unroll
    for (int ss = 0; ss < 8; ss++) yr[ss] = y1[(size_t)nbase * 64 + ss * 8 + l8];

    for (int n = 0; n < 8; n++) {
        int i = nbase + n;
        if (n < 7) {
            stage_rows(xvp, knn, i + 1, vbuf[wv][(n + 1) & 1], lane);
            if (lane < 32)
                *(float4*)&wbuf[wv][(n + 1) & 1][lane * 4] =
                    *(const float4*)(w1b + (size_t)(i + 1) * 128 + lane * 4);
#pragma unroll
            for (int ss = 0; ss < 8; ss++) yrn[ss] = y1[(size_t)(i + 1) * 64 + ss * 8 + l8];
        }
        const float* vb = vbuf[wv][n & 1];
        const float* wb = wbuf[wv][n & 1];

        float a[2];
#pragma unroll
        for (int r = 0; r < 2; r++) {
            int k = kg + r * 8;
            float w1v[8];
            *(float4*)&w1v[0] = *(const float4*)(wb + k * 8);
            *(float4*)&w1v[4] = *(const float4*)(wb + k * 8 + 4);
            float acc = 0.f;
#pragma unroll
            for (int e = 0; e < 8; e++) {
                float v = fmaxf(w1v[e] * sc1[e] + sh1[e], 0.f);
                acc += v * w2c[e];
            }
            a[r] = acc;
        }
        float mx = fmaxf(a[0], a[1]);
#pragma unroll
        for (int off = 8; off <= 32; off <<= 1) mx = fmaxf(mx, __shfl_xor(mx, off));
        float e0 = __expf(a[0] - mx), e1 = __expf(a[1] - mx);
        float sum = e0 + e1;
#pragma unroll
        for (int off = 8; off <= 32; off <<= 1) sum += __shfl_xor(sum, off);
        float inv = 1.f / sum;
        float wg0 = e0 * inv, wg1 = e1 * inv;

        float acc[8];
#pragma unroll
        for (int ss = 0; ss < 8; ss++) acc[ss] = 0.f;
        {
            float v[8];
            read_seg(vb, kg, l8, v);
#pragma unroll
            for (int ss = 0; ss < 8; ss++) acc[ss] += wg0 * v[ss];
            read_seg(vb, kg + 8, l8, v);
#pragma unroll
            for (int ss = 0; ss < 8; ss++) acc[ss] += wg1 * v[ss];
        }
#pragma unroll
        for (int off = 8; off <= 32; off <<= 1)
#pragma unroll
            for (int ss = 0; ss < 8; ss++) acc[ss] += __shfl_xor(acc[ss], off);

        if (kg == 0) {
#pragma unroll
            for (int ss = 0; ss < 8; ss++) {
                float xh = fmaxf(yr[ss] * sgr[ss] + shr[ss], 0.f);
                out[(size_t)i * 64 + ss * 8 + l8] = xh + acc[ss];
            }
        }
#pragma unroll
        for (int ss = 0; ss < 8; ss++) yr[ss] = yrn[ss];
    }
}

// ---------------------------------------------------------------------------
extern "C" void kernel_launch(void* const* d_in, const int* in_sizes, int n_in,
                              void* d_out, int out_size, void* d_ws, size_t ws_size,
                              hipStream_t stream)
{
    const float* p1   = (const float*)d_in[0];
    const float* x1   = (const float*)d_in[1];
    const float* p2   = (const float*)d_in[2];
    const float* x2   = (const float*)d_in[3];
    const int*   knn  = (const int*)d_in[4];
    const int*   iidx = (const int*)d_in[5];
    const float* W1   = (const float*)d_in[6];
    const float* g1   = (const float*)d_in[8];
    const float* be1  = (const float*)d_in[9];
    const float* W2   = (const float*)d_in[10];
    const float* g2   = (const float*)d_in[12];
    const float* be2  = (const float*)d_in[13];
    const float* Wq   = (const float*)d_in[14];
    const float* bq   = (const float*)d_in[15];
    const float* Wk   = (const float*)d_in[16];
    const float* Wv   = (const float*)d_in[18];
    const float* bv   = (const float*)d_in[19];
    const float* gw0  = (const float*)d_in[20];
    const float* bw0  = (const float*)d_in[21];
    const float* Ww1  = (const float*)d_in[22];
    const float* gw1  = (const float*)d_in[24];
    const float* bew1 = (const float*)d_in[25];
    const float* Ww2  = (const float*)d_in[26];
    // b1, b2, bk, bw1, bw2 provably cancel (BN mean-subtraction / softmax shift)

    float* ws   = (float*)d_ws;
    float* y1   = ws + OFF_Y1;
    float* y2   = ws + OFF_Y2;
    float* xq   = ws + OFF_XQ;
    float* xk   = ws + OFF_XK;
    float* xvp  = ws + OFF_XVP;
    float* w1b  = ws + OFF_W1B;
    float* st1  = ws + OFF_ST;
    float* st2  = st1 + 128;
    float* st0  = st1 + 256;
    float* stw1 = st1 + 384;
    float* outp = (float*)d_out;

    hipMemsetAsync(st1, 0, 512 * sizeof(float), stream);

    stats12_k<<<938, 256, 0, stream>>>(x1, W1, x2, W2, y1, y2, st1, st2);
    qkv_k<<<1250, 256, 0, stream>>>(y1, st1, g1, be1, Wq, bq,
                                    p1, p2, iidx, y2, st2, g2, be2,
                                    Wk, Wv, bv, xq, xk, xvp);
    wstats_k<<<1250, 256, 0, stream>>>(xq, xk, knn, st0);
    wmlp1_k<<<1250, 256, 0, stream>>>(xq, xk, knn, st0, gw0, bw0, Ww1, w1b);
    w1stats_k<<<512, 256, 0, stream>>>(w1b, stw1);
    attn_k<<<1250, 256, 0, stream>>>(w1b, stw1, gw1, bew1, Ww2, knn, xvp,
                                     y1, st1, g1, be1, outp);
}

// Round 5
// 264.063 us; speedup vs baseline: 1.4434x; 1.2003x over previous
//
#include <hip/hip_runtime.h>
#include <hip/hip_fp16.h>
#include <cstdint>
#include <cstddef>

static constexpr int N1 = 40000;
static constexpr int N2 = 10000;
static constexpr int KNN = 16;
static constexpr float EPS = 1e-5f;

// Workspace layout (float offsets; fp16 regions reinterpret the same slots)
static constexpr size_t OFF_Y1   = 0;          // N1*64 f32 raw linear1 output
static constexpr size_t OFF_Y2   = 2560000;    // N2*64 f32 raw linear2 output
static constexpr size_t OFF_XQ   = 5760000;    // N1*64 f32
static constexpr size_t OFF_XKH  = 8320000;    // N1*64 __half
static constexpr size_t OFF_XVPH = 10880000;   // N1*64 __half (PERMUTED [j][d*8+s])
static constexpr size_t OFF_W1BH = 13440000;   // N1*16*8 __half
static constexpr size_t OFF_ST   = 18560000;   // st1(128) st2(128) st0(128) stw1(16)

union F4H8 { float4 f4; __half2 h2[4]; };

__device__ __forceinline__ void cvt8(float4 raw, float* u) {
    F4H8 c; c.f4 = raw;
#pragma unroll
    for (int t = 0; t < 4; t++) {
        float2 f = __half22float2(c.h2[t]);
        u[2 * t] = f.x; u[2 * t + 1] = f.y;
    }
}

__device__ __forceinline__ float4 pack8(const float* p) {
    F4H8 c;
#pragma unroll
    for (int t = 0; t < 4; t++) c.h2[t] = __floats2half2_rn(p[2 * t], p[2 * t + 1]);
    return c.f4;
}

// ---------------------------------------------------------------------------
// Fused GEMM + column stats for linear1 (CIN=64) and linear2 (CIN=128).
// Biases dropped (BN cancels). blocks [0,625) -> l1, [625,938) -> l2.
// ---------------------------------------------------------------------------
template<int CIN, int RPT>
__device__ __forceinline__ void gemm_stats_body(const float* __restrict__ X,
                                                const float* __restrict__ W,
                                                float* __restrict__ Y,
                                                float* __restrict__ stats,
                                                int N, int bidx, float* sm)
{
    constexpr int ROWS = 16 * RPT;
    constexpr int XST = CIN + 4;
    float* Ws = sm;
    float* Xs = sm + CIN * 64;

    for (int t = threadIdx.x; t < CIN * 64; t += 256) Ws[t] = W[t];
    const int base = bidx * ROWS;
    for (int f = threadIdx.x; f < ROWS * CIN / 4; f += 256) {
        int e = f * 4;
        int r = e / CIN, col = e % CIN;
        int grow = base + r;
        float4 v = make_float4(0.f, 0.f, 0.f, 0.f);
        if (grow < N) v = *(const float4*)(X + (size_t)grow * CIN + col);
        *(float4*)(Xs + r * XST + col) = v;
    }
    __syncthreads();

    const int cg = threadIdx.x & 15, rg = threadIdx.x >> 4;
    float acc[RPT][4];
#pragma unroll
    for (int j = 0; j < RPT; j++)
        acc[j][0] = acc[j][1] = acc[j][2] = acc[j][3] = 0.f;
#pragma unroll 8
    for (int k = 0; k < CIN; k++) {
        float4 w4 = *(const float4*)&Ws[k * 64 + cg * 4];
#pragma unroll
        for (int j = 0; j < RPT; j++) {
            float x = Xs[(rg * RPT + j) * XST + k];
            acc[j][0] += x * w4.x; acc[j][1] += x * w4.y;
            acc[j][2] += x * w4.z; acc[j][3] += x * w4.w;
        }
    }

    float s[4] = {0.f, 0.f, 0.f, 0.f}, s2[4] = {0.f, 0.f, 0.f, 0.f};
#pragma unroll
    for (int j = 0; j < RPT; j++) {
        int r = base + rg * RPT + j;
        if (r < N) {
            *(float4*)(Y + (size_t)r * 64 + cg * 4) =
                make_float4(acc[j][0], acc[j][1], acc[j][2], acc[j][3]);
#pragma unroll
            for (int m = 0; m < 4; m++) { s[m] += acc[j][m]; s2[m] += acc[j][m] * acc[j][m]; }
        }
    }
    __syncthreads();
    float* red = Ws;
    *(float4*)&red[rg * 64 + cg * 4] = make_float4(s[0], s[1], s[2], s[3]);
    __syncthreads();
    if (threadIdx.x < 64) {
        float t = 0.f;
#pragma unroll
        for (int g = 0; g < 16; g++) t += red[g * 64 + threadIdx.x];
        atomicAdd(&stats[threadIdx.x], t);
    }
    __syncthreads();
    *(float4*)&red[rg * 64 + cg * 4] = make_float4(s2[0], s2[1], s2[2], s2[3]);
    __syncthreads();
    if (threadIdx.x < 64) {
        float t = 0.f;
#pragma unroll
        for (int g = 0; g < 16; g++) t += red[g * 64 + threadIdx.x];
        atomicAdd(&stats[64 + threadIdx.x], t);
    }
}

__global__ __launch_bounds__(256) void stats12_k(const float* __restrict__ x1,
                                                 const float* __restrict__ W1,
                                                 const float* __restrict__ x2,
                                                 const float* __restrict__ W2,
                                                 float* __restrict__ y1,
                                                 float* __restrict__ y2,
                                                 float* __restrict__ st1,
                                                 float* __restrict__ st2)
{
    __shared__ float sm[128 * 64 + 32 * 132];
    if (blockIdx.x < 625)
        gemm_stats_body<64, 4>(x1, W1, y1, st1, N1, blockIdx.x, sm);
    else
        gemm_stats_body<128, 2>(x2, W2, y2, st2, N2, blockIdx.x - 625, sm);
}

// ---------------------------------------------------------------------------
// qkv: blocks [0,625): xq = relu(bn1(y1)) @ Wq + bq (f32 out)
//      blocks [625,1250): x2i = interp(relu(bn2(y2)));
//        xkh = fp16(x2i@Wk); xvph = fp16(perm(x2i@Wv + bv))
// LDS: [W_a 4096][W_b 4096][Xs 64x68=4352][cst 128] ; cst at 12544!
// ---------------------------------------------------------------------------
__global__ __launch_bounds__(256) void qkv_k(const float* __restrict__ y1,
                                             const float* __restrict__ st1,
                                             const float* __restrict__ g1,
                                             const float* __restrict__ be1,
                                             const float* __restrict__ Wq,
                                             const float* __restrict__ bq,
                                             const float* __restrict__ p1,
                                             const float* __restrict__ p2,
                                             const int* __restrict__ iidx,
                                             const float* __restrict__ y2,
                                             const float* __restrict__ st2,
                                             const float* __restrict__ g2,
                                             const float* __restrict__ be2,
                                             const float* __restrict__ Wk_,
                                             const float* __restrict__ Wv_,
                                             const float* __restrict__ bv_,
                                             float* __restrict__ xq,
                                             __half* __restrict__ xkh,
                                             __half* __restrict__ xvph)
{
    __shared__ float sm[12672];
    const int cg = threadIdx.x & 15, rg = threadIdx.x >> 4;

    if (blockIdx.x < 625) {
        float* Ws = sm;
        float* Xs = sm + 4096;
        float* cst = sm + 12544;
        for (int t = threadIdx.x; t < 4096; t += 256) Ws[t] = Wq[t];
        if (threadIdx.x < 64) {
            int c = threadIdx.x;
            float mean = st1[c] * (1.f / N1);
            float var = st1[64 + c] * (1.f / N1) - mean * mean;
            float sg = g1[c] * rsqrtf(var + EPS);
            cst[c] = sg; cst[64 + c] = be1[c] - mean * sg;
        }
        __syncthreads();
        const int base = blockIdx.x * 64;
        for (int f = threadIdx.x; f < 1024; f += 256) {
            int r = f >> 4, col = (f & 15) * 4;
            float4 v = *(const float4*)(y1 + (size_t)(base + r) * 64 + col);
            Xs[r * 68 + col + 0] = fmaxf(v.x * cst[col] + cst[64 + col], 0.f);
            Xs[r * 68 + col + 1] = fmaxf(v.y * cst[col + 1] + cst[64 + col + 1], 0.f);
            Xs[r * 68 + col + 2] = fmaxf(v.z * cst[col + 2] + cst[64 + col + 2], 0.f);
            Xs[r * 68 + col + 3] = fmaxf(v.w * cst[col + 3] + cst[64 + col + 3], 0.f);
        }
        __syncthreads();
        float4 bb = *(const float4*)(bq + cg * 4);
        float acc[4][4];
#pragma unroll
        for (int j = 0; j < 4; j++) {
            acc[j][0] = bb.x; acc[j][1] = bb.y; acc[j][2] = bb.z; acc[j][3] = bb.w;
        }
#pragma unroll 8
        for (int k = 0; k < 64; k++) {
            float4 w4 = *(const float4*)&Ws[k * 64 + cg * 4];
#pragma unroll
            for (int j = 0; j < 4; j++) {
                float x = Xs[(rg * 4 + j) * 68 + k];
                acc[j][0] += x * w4.x; acc[j][1] += x * w4.y;
                acc[j][2] += x * w4.z; acc[j][3] += x * w4.w;
            }
        }
#pragma unroll
        for (int j = 0; j < 4; j++) {
            int r = base + rg * 4 + j;
            *(float4*)(xq + (size_t)r * 64 + cg * 4) =
                make_float4(acc[j][0], acc[j][1], acc[j][2], acc[j][3]);
        }
    } else {
        float* Wks = sm;
        float* Wvs = sm + 4096;
        float* Xs = sm + 8192;
        float* cst = sm + 12544;
        for (int t = threadIdx.x; t < 4096; t += 256) { Wks[t] = Wk_[t]; Wvs[t] = Wv_[t]; }
        if (threadIdx.x < 64) {
            int c = threadIdx.x;
            float mean = st2[c] * (1.f / N2);
            float var = st2[64 + c] * (1.f / N2) - mean * mean;
            float sg = g2[c] * rsqrtf(var + EPS);
            cst[c] = sg; cst[64 + c] = be2[c] - mean * sg;
        }
        __syncthreads();
        const int base = (blockIdx.x - 625) * 64;
        {
            int row = threadIdx.x >> 2, q4 = threadIdx.x & 3;
            int gi = base + row;
            int j0 = iidx[gi * 3 + 0], j1 = iidx[gi * 3 + 1], j2 = iidx[gi * 3 + 2];
            float ax = p1[gi * 3 + 0], ay = p1[gi * 3 + 1], az = p1[gi * 3 + 2];
            float dx, dy, dz;
            dx = ax - p2[j0 * 3 + 0]; dy = ay - p2[j0 * 3 + 1]; dz = az - p2[j0 * 3 + 2];
            float w0 = 1.f / (sqrtf(dx * dx + dy * dy + dz * dz) + 1e-8f);
            dx = ax - p2[j1 * 3 + 0]; dy = ay - p2[j1 * 3 + 1]; dz = az - p2[j1 * 3 + 2];
            float w1 = 1.f / (sqrtf(dx * dx + dy * dy + dz * dz) + 1e-8f);
            dx = ax - p2[j2 * 3 + 0]; dy = ay - p2[j2 * 3 + 1]; dz = az - p2[j2 * 3 + 2];
            float w2 = 1.f / (sqrtf(dx * dx + dy * dy + dz * dz) + 1e-8f);
            float inv = 1.f / (w0 + w1 + w2);
            w0 *= inv; w1 *= inv; w2 *= inv;
#pragma unroll
            for (int c4 = 0; c4 < 4; c4++) {
                int col = q4 * 16 + c4 * 4;
                float4 a = *(const float4*)(y2 + (size_t)j0 * 64 + col);
                float4 b = *(const float4*)(y2 + (size_t)j1 * 64 + col);
                float4 c = *(const float4*)(y2 + (size_t)j2 * 64 + col);
                float4 o;
                o.x = w0 * fmaxf(a.x * cst[col] + cst[64 + col], 0.f)
                    + w1 * fmaxf(b.x * cst[col] + cst[64 + col], 0.f)
                    + w2 * fmaxf(c.x * cst[col] + cst[64 + col], 0.f);
                o.y = w0 * fmaxf(a.y * cst[col + 1] + cst[64 + col + 1], 0.f)
                    + w1 * fmaxf(b.y * cst[col + 1] + cst[64 + col + 1], 0.f)
                    + w2 * fmaxf(c.y * cst[col + 1] + cst[64 + col + 1], 0.f);
                o.z = w0 * fmaxf(a.z * cst[col + 2] + cst[64 + col + 2], 0.f)
                    + w1 * fmaxf(b.z * cst[col + 2] + cst[64 + col + 2], 0.f)
                    + w2 * fmaxf(c.z * cst[col + 2] + cst[64 + col + 2], 0.f);
                o.w = w0 * fmaxf(a.w * cst[col + 3] + cst[64 + col + 3], 0.f)
                    + w1 * fmaxf(b.w * cst[col + 3] + cst[64 + col + 3], 0.f)
                    + w2 * fmaxf(c.w * cst[col + 3] + cst[64 + col + 3], 0.f);
                *(float4*)(Xs + row * 68 + col) = o;
            }
        }
        __syncthreads();
        float4 bv4 = *(const float4*)(bv_ + cg * 4);
        float ak[4][4], av[4][4];
#pragma unroll
        for (int j = 0; j < 4; j++) {
            ak[j][0] = ak[j][1] = ak[j][2] = ak[j][3] = 0.f;
            av[j][0] = bv4.x; av[j][1] = bv4.y; av[j][2] = bv4.z; av[j][3] = bv4.w;
        }
#pragma unroll 4
        for (int k = 0; k < 64; k++) {
            float4 wk4 = *(const float4*)&Wks[k * 64 + cg * 4];
            float4 wv4 = *(const float4*)&Wvs[k * 64 + cg * 4];
#pragma unroll
            for (int j = 0; j < 4; j++) {
                float x = Xs[(rg * 4 + j) * 68 + k];
                ak[j][0] += x * wk4.x; ak[j][1] += x * wk4.y;
                ak[j][2] += x * wk4.z; ak[j][3] += x * wk4.w;
                av[j][0] += x * wv4.x; av[j][1] += x * wv4.y;
                av[j][2] += x * wv4.z; av[j][3] += x * wv4.w;
            }
        }
        // xk fp16 direct store (8B per thread-row)
#pragma unroll
        for (int j = 0; j < 4; j++) {
            int r = base + rg * 4 + j;
            union { uint2 u; __half2 h[2]; } pk;
            pk.h[0] = __floats2half2_rn(ak[j][0], ak[j][1]);
            pk.h[1] = __floats2half2_rn(ak[j][2], ak[j][3]);
            *(uint2*)(xkh + (size_t)r * 64 + cg * 4) = pk.u;
        }
        // xvp fp16 via LDS bounce (scatter halves, then coalesced copy-out)
        __syncthreads();                    // done reading Wks/Wvs
        __half* hb = (__half*)sm;           // 64 rows x 64 halves = 8 KB
#pragma unroll
        for (int j = 0; j < 4; j++) {
            int rl = rg * 4 + j;
#pragma unroll
            for (int m = 0; m < 4; m++) {
                int c = cg * 4 + m;
                int pc = (c & 7) * 8 + (c >> 3);
                hb[rl * 64 + pc] = __float2half_rn(av[j][m]);
            }
        }
        __syncthreads();
        for (int f = threadIdx.x; f < 512; f += 256) {
            float4 v = *(const float4*)((const char*)hb + f * 16);
            ((float4*)(xvph + (size_t)base * 64))[f] = v;
        }
    }
}

// ---------------------------------------------------------------------------
// wstats: per-channel sum/sumsq of w = xk[knn]-xq. lane=(k8=lane>>3, ch=lane&7),
// register-resident fp16 gather: 2 dwordx4/node cover all 16 rows; depth-2 pipe.
// ---------------------------------------------------------------------------
__global__ __launch_bounds__(256) void wstats_k(const float* __restrict__ xq,
                                                const __half* __restrict__ xkh,
                                                const int* __restrict__ knn,
                                                float* __restrict__ st0)
{
    __shared__ int ibuf[4][128];
    __shared__ float red[4][128];
    const int lane = threadIdx.x & 63, wv = threadIdx.x >> 6;
    const int k8 = lane >> 3, ch = lane & 7;
    const int nbase = blockIdx.x * 32 + wv * 8;

    ibuf[wv][lane] = knn[nbase * 16 + lane];
    ibuf[wv][64 + lane] = knn[nbase * 16 + 64 + lane];

    float s[8], s2[8];
#pragma unroll
    for (int m = 0; m < 8; m++) { s[m] = 0.f; s2[m] = 0.f; }

    int j0 = ibuf[wv][k8], j1 = ibuf[wv][k8 + 8];
    float4 r0c = ((const float4*)(xkh + (size_t)j0 * 64))[ch];
    float4 r1c = ((const float4*)(xkh + (size_t)j1 * 64))[ch];
    float4 qac = *(const float4*)(xq + (size_t)nbase * 64 + ch * 8);
    float4 qbc = *(const float4*)(xq + (size_t)nbase * 64 + ch * 8 + 4);

#pragma unroll
    for (int n = 0; n < 8; n++) {
        float4 r0n = {}, r1n = {}, qan = {}, qbn = {};
        if (n < 7) {
            int ja = ibuf[wv][(n + 1) * 16 + k8], jb = ibuf[wv][(n + 1) * 16 + k8 + 8];
            r0n = ((const float4*)(xkh + (size_t)ja * 64))[ch];
            r1n = ((const float4*)(xkh + (size_t)jb * 64))[ch];
            qan = *(const float4*)(xq + (size_t)(nbase + n + 1) * 64 + ch * 8);
            qbn = *(const float4*)(xq + (size_t)(nbase + n + 1) * 64 + ch * 8 + 4);
        }
        float qv[8] = {qac.x, qac.y, qac.z, qac.w, qbc.x, qbc.y, qbc.z, qbc.w};
        float u[8];
        cvt8(r0c, u);
#pragma unroll
        for (int m = 0; m < 8; m++) { float w = u[m] - qv[m]; s[m] += w; s2[m] += w * w; }
        cvt8(r1c, u);
#pragma unroll
        for (int m = 0; m < 8; m++) { float w = u[m] - qv[m]; s[m] += w; s2[m] += w * w; }
        r0c = r0n; r1c = r1n; qac = qan; qbc = qbn;
    }
#pragma unroll
    for (int off = 8; off <= 32; off <<= 1)
#pragma unroll
        for (int m = 0; m < 8; m++) {
            s[m] += __shfl_xor(s[m], off);
            s2[m] += __shfl_xor(s2[m], off);
        }
    if (k8 == 0) {
#pragma unroll
        for (int m = 0; m < 8; m++) {
            red[wv][ch * 8 + m] = s[m];
            red[wv][64 + ch * 8 + m] = s2[m];
        }
    }
    __syncthreads();
    if (threadIdx.x < 128) {
        float t = red[0][threadIdx.x] + red[1][threadIdx.x] +
                  red[2][threadIdx.x] + red[3][threadIdx.x];
        atomicAdd(&st0[threadIdx.x], t);
    }
}

// ---------------------------------------------------------------------------
// wmlp1: w1[i,k,:] = relu(bn0(xk[knn]-xq)) @ Ww1 (fp16 out) + fused w1 stats.
// lane=(k8,ch): lane owns channels ch*8..+7, rows k8 and k8+8.
// ---------------------------------------------------------------------------
__global__ __launch_bounds__(256) void wmlp1_k(const float* __restrict__ xq,
                                               const __half* __restrict__ xkh,
                                               const int* __restrict__ knn,
                                               const float* __restrict__ st0,
                                               const float* __restrict__ gw0,
                                               const float* __restrict__ bw0,
                                               const float* __restrict__ Ww1,
                                               __half* __restrict__ w1bh,
                                               float* __restrict__ stw1)
{
    __shared__ int ibuf[4][128];
    __shared__ float red[4][16];
    const int lane = threadIdx.x & 63, wv = threadIdx.x >> 6;
    const int k8 = lane >> 3, ch = lane & 7;
    const int nbase = blockIdx.x * 32 + wv * 8;
    const float cinv = 1.f / (float)(N1 * KNN);

    ibuf[wv][lane] = knn[nbase * 16 + lane];
    ibuf[wv][64 + lane] = knn[nbase * 16 + 64 + lane];

    float sc0[8], sh0[8];
#pragma unroll
    for (int m = 0; m < 8; m++) {
        int c = ch * 8 + m;
        float mean = st0[c] * cinv;
        float var = st0[64 + c] * cinv - mean * mean;
        float sg = gw0[c] * rsqrtf(var + EPS);
        sc0[m] = sg; sh0[m] = bw0[c] - mean * sg;
    }
    float wW[8][8];
#pragma unroll
    for (int m = 0; m < 8; m++) {
        *(float4*)&wW[m][0] = *(const float4*)(Ww1 + (ch * 8 + m) * 8);
        *(float4*)&wW[m][4] = *(const float4*)(Ww1 + (ch * 8 + m) * 8 + 4);
    }
    float sacc[8], s2acc[8];
#pragma unroll
    for (int d = 0; d < 8; d++) { sacc[d] = 0.f; s2acc[d] = 0.f; }

    int j0 = ibuf[wv][k8], j1 = ibuf[wv][k8 + 8];
    float4 r0c = ((const float4*)(xkh + (size_t)j0 * 64))[ch];
    float4 r1c = ((const float4*)(xkh + (size_t)j1 * 64))[ch];
    float4 qac = *(const float4*)(xq + (size_t)nbase * 64 + ch * 8);
    float4 qbc = *(const float4*)(xq + (size_t)nbase * 64 + ch * 8 + 4);

#pragma unroll
    for (int n = 0; n < 8; n++) {
        const int i = nbase + n;
        float4 r0n = {}, r1n = {}, qan = {}, qbn = {};
        if (n < 7) {
            int ja = ibuf[wv][(n + 1) * 16 + k8], jb = ibuf[wv][(n + 1) * 16 + k8 + 8];
            r0n = ((const float4*)(xkh + (size_t)ja * 64))[ch];
            r1n = ((const float4*)(xkh + (size_t)jb * 64))[ch];
            qan = *(const float4*)(xq + (size_t)(i + 1) * 64 + ch * 8);
            qbn = *(const float4*)(xq + (size_t)(i + 1) * 64 + ch * 8 + 4);
        }
        float qv[8] = {qac.x, qac.y, qac.z, qac.w, qbc.x, qbc.y, qbc.z, qbc.w};
        float qsh[8];
#pragma unroll
        for (int m = 0; m < 8; m++) qsh[m] = sh0[m] - qv[m] * sc0[m];

#pragma unroll
        for (int r = 0; r < 2; r++) {
            float u[8];
            cvt8(r ? r1c : r0c, u);
            float p[8];
#pragma unroll
            for (int d = 0; d < 8; d++) p[d] = 0.f;
#pragma unroll
            for (int m = 0; m < 8; m++) {
                float t = fmaxf(u[m] * sc0[m] + qsh[m], 0.f);
#pragma unroll
                for (int d = 0; d < 8; d++) p[d] += t * wW[m][d];
            }
#pragma unroll
            for (int d = 0; d < 8; d++) p[d] += __shfl_xor(p[d], 1);
#pragma unroll
            for (int d = 0; d < 8; d++) p[d] += __shfl_xor(p[d], 2);
#pragma unroll
            for (int d = 0; d < 8; d++) p[d] += __shfl_xor(p[d], 4);
#pragma unroll
            for (int d = 0; d < 8; d++) { sacc[d] += p[d]; s2acc[d] += p[d] * p[d]; }
            if (ch == 0) {
                float4 raw = pack8(p);
                *(float4*)(w1bh + ((size_t)i * 16 + k8 + r * 8) * 8) = raw;
            }
        }
        r0c = r0n; r1c = r1n; qac = qan; qbc = qbn;
    }
    // stats: every ch lane holds identical (k8-local) totals; sum over k8 groups
#pragma unroll
    for (int off = 8; off <= 32; off <<= 1)
#pragma unroll
        for (int d = 0; d < 8; d++) {
            sacc[d] += __shfl_xor(sacc[d], off);
            s2acc[d] += __shfl_xor(s2acc[d], off);
        }
    if (lane == 0) {
#pragma unroll
        for (int d = 0; d < 8; d++) { red[wv][d] = sacc[d]; red[wv][8 + d] = s2acc[d]; }
    }
    __syncthreads();
    if (threadIdx.x < 16) {
        float t = red[0][threadIdx.x] + red[1][threadIdx.x] +
                  red[2][threadIdx.x] + red[3][threadIdx.x];
        atomicAdd(&stw1[threadIdx.x], t);
    }
}

// ---------------------------------------------------------------------------
// attn: bn1+relu -> @Ww2 -> softmax over k -> weighted xvp agg -> + residual.
// lane=(k8,ch): d = ch; logits for k=k8,k8+8; fp16 gathers; LDS bounce epilogue.
// ---------------------------------------------------------------------------
__global__ __launch_bounds__(256) void attn_k(const __half* __restrict__ w1bh,
                                              const float* __restrict__ stw1,
                                              const float* __restrict__ gw1,
                                              const float* __restrict__ bew1,
                                              const float* __restrict__ Ww2,
                                              const int* __restrict__ knn,
                                              const __half* __restrict__ xvph,
                                              const float* __restrict__ y1,
                                              const float* __restrict__ st1,
                                              const float* __restrict__ g1,
                                              const float* __restrict__ be1,
                                              float* __restrict__ out)
{
    __shared__ int ibuf[4][128];
    __shared__ float rbuf[4][64];
    const int lane = threadIdx.x & 63, wv = threadIdx.x >> 6;
    const int k8 = lane >> 3, ch = lane & 7;
    const int nbase = blockIdx.x * 32 + wv * 8;
    const float cinv = 1.f / (float)(N1 * KNN);

    ibuf[wv][lane] = knn[nbase * 16 + lane];
    ibuf[wv][64 + lane] = knn[nbase * 16 + 64 + lane];

    float sc1[8], sh1[8];
#pragma unroll
    for (int e = 0; e < 8; e++) {
        float mean = stw1[e] * cinv;
        float var = stw1[8 + e] * cinv - mean * mean;
        float sg = gw1[e] * rsqrtf(var + EPS);
        sc1[e] = sg; sh1[e] = bew1[e] - mean * sg;
    }
    float w2c[8];
#pragma unroll
    for (int e = 0; e < 8; e++) w2c[e] = Ww2[e * 8 + ch];

    // residual BN consts for channel = lane
    float meanr = st1[lane] * (1.f / N1);
    float varr = st1[64 + lane] * (1.f / N1) - meanr * meanr;
    float sgr = g1[lane] * rsqrtf(varr + EPS);
    float shr = be1[lane] - meanr * sgr;

    int j0 = ibuf[wv][k8], j1 = ibuf[wv][k8 + 8];
    float4 v0c = ((const float4*)(xvph + (size_t)j0 * 64))[ch];
    float4 v1c = ((const float4*)(xvph + (size_t)j1 * 64))[ch];
    float4 w0c = *(const float4*)(w1bh + ((size_t)nbase * 16 + k8) * 8);
    float4 w1c = *(const float4*)(w1bh + ((size_t)nbase * 16 + k8 + 8) * 8);
    float yc = y1[(size_t)nbase * 64 + lane];

#pragma unroll
    for (int n = 0; n < 8; n++) {
        const int i = nbase + n;
        float4 v0n = {}, v1n = {}, w0n = {}, w1n = {};
        float yn = 0.f;
        if (n < 7) {
            int ja = ibuf[wv][(n + 1) * 16 + k8], jb = ibuf[wv][(n + 1) * 16 + k8 + 8];
            v0n = ((const float4*)(xvph + (size_t)ja * 64))[ch];
            v1n = ((const float4*)(xvph + (size_t)jb * 64))[ch];
            w0n = *(const float4*)(w1bh + ((size_t)(i + 1) * 16 + k8) * 8);
            w1n = *(const float4*)(w1bh + ((size_t)(i + 1) * 16 + k8 + 8) * 8);
            yn = y1[(size_t)(i + 1) * 64 + lane];
        }
        float w1v[8];
        cvt8(w0c, w1v);
        float a0 = 0.f;
#pragma unroll
        for (int e = 0; e < 8; e++)
            a0 += fmaxf(w1v[e] * sc1[e] + sh1[e], 0.f) * w2c[e];
        cvt8(w1c, w1v);
        float a1 = 0.f;
#pragma unroll
        for (int e = 0; e < 8; e++)
            a1 += fmaxf(w1v[e] * sc1[e] + sh1[e], 0.f) * w2c[e];

        float mx = fmaxf(a0, a1);
#pragma unroll
        for (int off = 8; off <= 32; off <<= 1) mx = fmaxf(mx, __shfl_xor(mx, off));
        float e0 = __expf(a0 - mx), e1 = __expf(a1 - mx);
        float sum = e0 + e1;
#pragma unroll
        for (int off = 8; off <= 32; off <<= 1) sum += __shfl_xor(sum, off);
        float inv = 1.f / sum;
        float wg0 = e0 * inv, wg1 = e1 * inv;

        float v[8], acc[8];
        cvt8(v0c, v);
#pragma unroll
        for (int s = 0; s < 8; s++) acc[s] = wg0 * v[s];
        cvt8(v1c, v);
#pragma unroll
        for (int s = 0; s < 8; s++) acc[s] += wg1 * v[s];
#pragma unroll
        for (int off = 8; off <= 32; off <<= 1)
#pragma unroll
            for (int s = 0; s < 8; s++) acc[s] += __shfl_xor(acc[s], off);

        if (k8 == 0) {
#pragma unroll
            for (int s = 0; s < 8; s++) rbuf[wv][s * 8 + ch] = acc[s];
        }
        float xh = fmaxf(yc * sgr + shr, 0.f);
        out[(size_t)i * 64 + lane] = xh + rbuf[wv][lane];

        v0c = v0n; v1c = v1n; w0c = w0n; w1c = w1n; yc = yn;
    }
}

// ---------------------------------------------------------------------------
extern "C" void kernel_launch(void* const* d_in, const int* in_sizes, int n_in,
                              void* d_out, int out_size, void* d_ws, size_t ws_size,
                              hipStream_t stream)
{
    const float* p1   = (const float*)d_in[0];
    const float* x1   = (const float*)d_in[1];
    const float* p2   = (const float*)d_in[2];
    const float* x2   = (const float*)d_in[3];
    const int*   knn  = (const int*)d_in[4];
    const int*   iidx = (const int*)d_in[5];
    const float* W1   = (const float*)d_in[6];
    const float* g1   = (const float*)d_in[8];
    const float* be1  = (const float*)d_in[9];
    const float* W2   = (const float*)d_in[10];
    const float* g2   = (const float*)d_in[12];
    const float* be2  = (const float*)d_in[13];
    const float* Wq   = (const float*)d_in[14];
    const float* bq   = (const float*)d_in[15];
    const float* Wk   = (const float*)d_in[16];
    const float* Wv   = (const float*)d_in[18];
    const float* bv   = (const float*)d_in[19];
    const float* gw0  = (const float*)d_in[20];
    const float* bw0  = (const float*)d_in[21];
    const float* Ww1  = (const float*)d_in[22];
    const float* gw1  = (const float*)d_in[24];
    const float* bew1 = (const float*)d_in[25];
    const float* Ww2  = (const float*)d_in[26];
    // b1, b2, bk, bw1, bw2 provably cancel (BN mean-subtraction / softmax shift)

    float* ws   = (float*)d_ws;
    float* y1   = ws + OFF_Y1;
    float* y2   = ws + OFF_Y2;
    float* xq   = ws + OFF_XQ;
    __half* xkh  = (__half*)(ws + OFF_XKH);
    __half* xvph = (__half*)(ws + OFF_XVPH);
    __half* w1bh = (__half*)(ws + OFF_W1BH);
    float* st1  = ws + OFF_ST;
    float* st2  = st1 + 128;
    float* st0  = st1 + 256;
    float* stw1 = st1 + 384;
    float* outp = (float*)d_out;

    hipMemsetAsync(st1, 0, 512 * sizeof(float), stream);

    stats12_k<<<938, 256, 0, stream>>>(x1, W1, x2, W2, y1, y2, st1, st2);
    qkv_k<<<1250, 256, 0, stream>>>(y1, st1, g1, be1, Wq, bq,
                                    p1, p2, iidx, y2, st2, g2, be2,
                                    Wk, Wv, bv, xq, xkh, xvph);
    wstats_k<<<1250, 256, 0, stream>>>(xq, xkh, knn, st0);
    wmlp1_k<<<1250, 256, 0, stream>>>(xq, xkh, knn, st0, gw0, bw0, Ww1, w1bh, stw1);
    attn_k<<<1250, 256, 0, stream>>>(w1bh, stw1, gw1, bew1, Ww2, knn, xvph,
                                     y1, st1, g1, be1, outp);
}